// Round 4
// baseline (4365.808 us; speedup 1.0000x reference)
//
#include <hip/hip_runtime.h>
#include <stdint.h>

#define OUTN   200000
#define HID    128
#define NSTEP  64
#define KTOP   50
#define NBINS  1024
#define CAP    4096
#define NBLK   256
#define NTHR   512
#define NWRD   6250     // OUTN/32 bitmask words

// dot of one 128-wide f32 row with f32 vector in LDS
__device__ __forceinline__ float dot128f(const float* __restrict__ w, const float* __restrict__ h){
  const float4* w4 = (const float4*)w;
  float acc = 0.f;
  #pragma unroll
  for (int k=0;k<32;k++){
    float4 q = w4[k];
    const float* hp = h + k*4;
    acc += q.x*hp[0] + q.y*hp[1] + q.z*hp[2] + q.w*hp[3];
  }
  return acc;
}

__device__ __forceinline__ int binOf(float l, float rlo, float rsc){
  float b = (l - rlo) * rsc;
  b = fminf(fmaxf(b, 0.f), (float)(NBINS-1));
  return (int)b;
}

// ---------- block reductions (512 threads = 8 waves) ----------
__device__ __forceinline__ void blockRed5(float& mx, float& mn, float& a, float& b, float& c,
                                          int tid, float* sm /*>=48*/){
  #pragma unroll
  for (int o=32;o;o>>=1){
    mx=fmaxf(mx,__shfl_xor(mx,o)); mn=fminf(mn,__shfl_xor(mn,o));
    a+=__shfl_xor(a,o); b+=__shfl_xor(b,o); c+=__shfl_xor(c,o);
  }
  __syncthreads();
  if ((tid&63)==0){ int w=tid>>6; sm[w*5+0]=mx; sm[w*5+1]=mn; sm[w*5+2]=a; sm[w*5+3]=b; sm[w*5+4]=c; }
  __syncthreads();
  int nw = blockDim.x>>6;
  if (tid==0){
    for (int k=1;k<nw;k++){
      sm[0]=fmaxf(sm[0],sm[k*5+0]); sm[1]=fminf(sm[1],sm[k*5+1]);
      sm[2]+=sm[k*5+2]; sm[3]+=sm[k*5+3]; sm[4]+=sm[k*5+4];
    }
  }
  __syncthreads();
  mx=sm[0]; mn=sm[1]; a=sm[2]; b=sm[3]; c=sm[4];
}

__device__ __forceinline__ void blockRedPair(float& p, int& i, int tid, float* smp, int* smi){
  __syncthreads();
  #pragma unroll
  for (int o=32;o;o>>=1){
    float p2=__shfl_xor(p,o); int i2=__shfl_xor(i,o);
    if (p2>p || (p2==p && i2<i)){ p=p2; i=i2; }
  }
  if ((tid&63)==0){ smp[tid>>6]=p; smi[tid>>6]=i; }
  __syncthreads();
  if (tid==0){
    for (int k=1;k<8;k++){
      if (smp[k]>smp[0] || (smp[k]==smp[0] && smi[k]<smi[0])){ smp[0]=smp[k]; smi[0]=smi[k]; }
    }
  }
  __syncthreads();
  p=smp[0]; i=smi[0];
}

__device__ __forceinline__ int blockRedSum(int v, int tid, int* smi){
  __syncthreads();
  #pragma unroll
  for (int o=32;o;o>>=1) v += __shfl_xor(v,o);
  if ((tid&63)==0) smi[tid>>6]=v;
  __syncthreads();
  if (tid==0){ int s=0; for(int k=0;k<8;k++) s+=smi[k]; smi[0]=s; }
  __syncthreads();
  return smi[0];
}

// highest bin bstar with count(bin>=bstar) >= K. outp[0]=bstar, outp[1]=count.
__device__ __forceinline__ void histSelect(unsigned* histL, unsigned* csum, int tid, int K, int* outp){
  int base = NBINS - 2*(tid+1);
  csum[tid] = histL[base] + histL[base+1];
  __syncthreads();
  for (int off=1; off<NTHR; off<<=1){
    unsigned add = (tid>=off) ? csum[tid-off] : 0u;
    __syncthreads();
    csum[tid] += add;
    __syncthreads();
  }
  unsigned pre = (tid==0)?0u:csum[tid-1];
  if (csum[tid] >= (unsigned)K && pre < (unsigned)K){
    unsigned run = pre; int bs = base;
    for (int b=base+1; b>=base; --b){
      run += histL[b];
      if (run >= (unsigned)K){ bs=b; break; }
    }
    outp[0]=bs; outp[1]=(int)run;
  }
  __syncthreads();
}

// ---------- kernels ----------
extern "C" __global__ void k_init(const int* __restrict__ x,
                                  const float* __restrict__ b_ih, const float* __restrict__ b_hh,
                                  unsigned* mask_bits, unsigned* inx_bits, unsigned* hist_g,
                                  unsigned* gcount, float* rparams, float* h_ws, float* c_ws)
{
  int tid = threadIdx.x;  // single block, 1024 threads
  for (int i=tid;i<NWRD;i+=1024){ mask_bits[i]=0xFFFFFFFFu; inx_bits[i]=0u; }
  for (int i=tid;i<NBINS;i+=1024) hist_g[i]=0u;
  if (tid==0){ *gcount=0u; rparams[0]=0.f; rparams[1]=0.f; }
  if (tid<HID){
    // state after reference step 0 (emb=0, h=c=0)
    float ig=b_ih[tid]       +b_hh[tid];
    float gg=b_ih[tid+2*HID] +b_hh[tid+2*HID];
    float og=b_ih[tid+3*HID] +b_hh[tid+3*HID];
    float si=1.f/(1.f+expf(-ig)), so=1.f/(1.f+expf(-og));
    float cn=si*tanhf(gg);
    c_ws[tid]=cn; h_ws[tid]=so*tanhf(cn);
  }
  __syncthreads();
  if (tid<200){
    int v = x[tid]-1;                       // 1-indexed items
    if (v>=0 && v<OUTN) atomicOr(&inx_bits[v>>5], 1u<<(v&31));
  }
}

extern "C" __global__ void __launch_bounds__(NTHR) k_logits(
    const float* __restrict__ W_out, const float* __restrict__ b_out,
    const unsigned* __restrict__ mask_bits, const float* __restrict__ h_ws,
    const float* __restrict__ rparams,
    float* __restrict__ l_ws, unsigned* __restrict__ hist_g, float* __restrict__ partials)
{
  __shared__ float    h_l[HID];
  __shared__ unsigned hl[NBINS];
  __shared__ float    smf[48];
  int tid=threadIdx.x, bid=blockIdx.x;
  if (tid<HID) h_l[tid]=h_ws[tid];
  for (int i=tid;i<NBINS;i+=NTHR) hl[i]=0u;
  __syncthreads();
  const float rlo=rparams[0], rsc=rparams[1];
  // balanced contiguous chunks: blocks 0..63 take 782 rows, rest 781
  int start = bid*781 + (bid<64 ? bid : 64);
  int cnt   = 781 + (bid<64 ? 1 : 0);
  float mx=-3e38f, mn=3e38f, se=0.f, sl=0.f, sl2=0.f;
  for (int j=tid;j<cnt;j+=NTHR){
    int row = start+j;
    float l = dot128f(W_out+(size_t)row*HID, h_l) + b_out[row];
    l_ws[row]=l;
    se += expf(l)-1.f; sl += l; sl2 += l*l;
    if ((mask_bits[row>>5]>>(row&31))&1u){
      mx=fmaxf(mx,l); mn=fminf(mn,l);
      atomicAdd(&hl[binOf(l,rlo,rsc)],1u);
    }
  }
  blockRed5(mx,mn,se,sl,sl2,tid,smf);
  if (tid==0){ float* p=&partials[bid*8]; p[0]=mx;p[1]=mn;p[2]=se;p[3]=sl;p[4]=sl2; }
  for (int i=tid;i<NBINS;i+=NTHR){ unsigned v=hl[i]; if (v) atomicAdd(&hist_g[i],v); }
}

extern "C" __global__ void __launch_bounds__(NTHR) k_emit(
    const float* __restrict__ l_ws, const unsigned* __restrict__ mask_bits,
    const unsigned* __restrict__ hist_g, const float* __restrict__ partials,
    const float* __restrict__ rparams,
    float* __restrict__ out, unsigned* __restrict__ cand, unsigned* __restrict__ gcount,
    int t)
{
  __shared__ unsigned hl[NBINS];
  __shared__ unsigned csum[NTHR];
  __shared__ float    smf[48];
  __shared__ int      s_sel[2];
  int tid=threadIdx.x, bid=blockIdx.x;
  float mx=-3e38f,mn=3e38f,se=0.f,sl=0.f,sl2=0.f;
  if (tid<NBLK){ const float* p=&partials[tid*8]; mx=p[0];mn=p[1];se=p[2];sl=p[3];sl2=p[4]; }
  for (int i=tid;i<NBINS;i+=NTHR) hl[i]=hist_g[i];
  blockRed5(mx,mn,se,sl,sl2,tid,smf);
  const float invS = 1.f/(2.0e5f + se);
  histSelect(hl,csum,tid,KTOP,s_sel);
  const int bstar=s_sel[0];
  const float rlo=rparams[0], rsc=rparams[1];
  const bool doComp = (s_sel[1]<=CAP) && (rsc>0.f);
  float* orow = out + 2*NSTEP + (size_t)t*OUTN;
  int start = bid*781 + (bid<64 ? bid : 64);
  int cnt   = 781 + (bid<64 ? 1 : 0);
  for (int j=tid;j<cnt;j+=NTHR){
    int row = start+j;
    float l = l_ws[row];
    bool m = (mask_bits[row>>5]>>(row&31))&1u;
    orow[row] = m ? expf(l)*invS : 0.f;
    if (doComp && m && binOf(l,rlo,rsc)>=bstar){
      unsigned pos = atomicAdd(gcount,1u);
      if (pos<CAP) cand[pos]=(unsigned)row;
    }
  }
}

extern "C" __global__ void __launch_bounds__(NTHR) k_select(
    const float* __restrict__ emb_t,
    const float* __restrict__ W_ih, const float* __restrict__ W_hh,
    const float* __restrict__ b_ih, const float* __restrict__ b_hh,
    const float* __restrict__ l_ws, const float* __restrict__ partials,
    unsigned* mask_bits, const unsigned* __restrict__ inx_bits,
    unsigned* hist_g, unsigned* cand, unsigned* gcount,
    float* rparams, float* h_ws, float* c_ws,
    float* __restrict__ out, int t)
{
  __shared__ unsigned hl[NBINS];
  __shared__ unsigned csum[NTHR];
  __shared__ float    smf[48];
  __shared__ float    smp[8];
  __shared__ int      smi[8];
  __shared__ int      s_sel[2];
  __shared__ int      s_nc, s_cnt;
  __shared__ float    emb_l[HID], h_l[HID], gates[4*HID];
  int tid=threadIdx.x;

  float mx=-3e38f,mn=3e38f,se=0.f,sl=0.f,sl2=0.f;
  if (tid<NBLK){ const float* p=&partials[tid*8]; mx=p[0];mn=p[1];se=p[2];sl=p[3];sl2=p[4]; }
  for (int i=tid;i<NBINS;i+=NTHR) hl[i]=hist_g[i];
  blockRed5(mx,mn,se,sl,sl2,tid,smf);
  const float gmax=mx, gmin=mn, slg=sl, sl2g=sl2;
  histSelect(hl,csum,tid,KTOP,s_sel);
  const float rsc=rparams[1];
  const bool doComp = (s_sel[1]<=CAP) && (rsc>0.f);
  int nc = doComp ? (int)*gcount : 0;
  bool ok = doComp && nc>=KTOP && nc<=CAP;

  if (!ok){
    if (gmin >= gmax){
      // all masked logits tied: top-K = lowest-index masked rows (jax stable tie-break)
      if (tid==0){
        int c=0;
        for (int i=0;i<OUTN && c<KTOP;i++)
          if ((mask_bits[i>>5]>>(i&31))&1u) cand[c++]=(unsigned)i;
        s_nc=c;
      }
    } else {
      // exact histogram over [gmin, gmax]
      for (int i=tid;i<NBINS;i+=NTHR) hl[i]=0u;
      __syncthreads();
      const float sc2 = (float)NBINS/(gmax-gmin);
      for (int i=tid;i<OUTN;i+=NTHR)
        if ((mask_bits[i>>5]>>(i&31))&1u)
          atomicAdd(&hl[binOf(l_ws[i],gmin,sc2)],1u);
      __syncthreads();
      histSelect(hl,csum,tid,KTOP,s_sel);
      int b2=s_sel[0], c2=s_sel[1];
      if (c2<=CAP){
        if (tid==0) s_cnt=0;
        __syncthreads();
        for (int i=tid;i<OUTN;i+=NTHR){
          if ((mask_bits[i>>5]>>(i&31))&1u && binOf(l_ws[i],gmin,sc2)>=b2){
            int p=atomicAdd(&s_cnt,1);
            if (p<CAP) cand[p]=(unsigned)i;
          }
        }
        __syncthreads();
        if (tid==0) s_nc = (s_cnt<CAP ? s_cnt : CAP);
      } else {
        // massive ties above threshold: index-order collect (stable tie-break)
        if (tid==0){
          int c=0;
          for (int i=0;i<OUTN && c<KTOP;i++)
            if (((mask_bits[i>>5]>>(i&31))&1u) && binOf(l_ws[i],gmin,sc2)>=b2) cand[c++]=(unsigned)i;
          s_nc=c;
        }
      }
    }
    __syncthreads();
    nc = s_nc;
  }

  // selection ordered by (l desc, idx asc) — monotone-equal to probs ordering
  float bp=-3.4e38f; int bi=0x7fffffff;
  float hp=-3.4e38f; int hidx=0x7fffffff;
  for (int j=tid;j<nc;j+=NTHR){
    int idx=(int)cand[j];
    float l=l_ws[idx];
    if (l>bp || (l==bp && idx<bi)){ bp=l; bi=idx; }
    if (((inx_bits[idx>>5]>>(idx&31))&1u) && (l>hp || (l==hp && idx<hidx))){ hp=l; hidx=idx; }
  }
  blockRedPair(bp,bi,tid,smp,smi);
  blockRedPair(hp,hidx,tid,smp,smi);
  int a, fb;
  if (hidx != 0x7fffffff){
    int cnt=0;
    for (int j=tid;j<nc;j+=NTHR){
      int idx=(int)cand[j];
      float l=l_ws[idx];
      cnt += (l>hp || (l==hp && idx<hidx)) ? 1 : 0;
    }
    cnt = blockRedSum(cnt,tid,smi);
    if (cnt < KTOP){ a=hidx; fb=1; } else { a=bi; fb=-1; }
  } else { a=bi; fb=-1; }
  if (a<0 || a>=OUTN) a=0;          // safety clamp: never fault on a gather

  if (tid==0){
    out[t]       = (float)a;
    out[NSTEP+t] = (float)fb;
    atomicAnd(&mask_bits[a>>5], ~(1u<<(a&31)));
  }

  // LSTM update
  if (tid<HID){
    h_l[tid]  = h_ws[tid];
    emb_l[tid]= emb_t[(size_t)a*HID+tid] * (float)fb;
  }
  __syncthreads();
  float g = dot128f(W_ih+(size_t)tid*HID, emb_l) + dot128f(W_hh+(size_t)tid*HID, h_l)
          + b_ih[tid] + b_hh[tid];
  gates[tid]=g;
  __syncthreads();
  if (tid<HID){
    float ig=gates[tid], fg=gates[tid+HID], gg=gates[tid+2*HID], og=gates[tid+3*HID];
    float si=1.f/(1.f+expf(-ig)), sf=1.f/(1.f+expf(-fg)), so=1.f/(1.f+expf(-og));
    float cn=sf*c_ws[tid]+si*tanhf(gg);
    float hn=so*tanhf(cn);
    c_ws[tid]=cn; h_ws[tid]=hn;
  }

  // housekeeping for next step
  for (int i=tid;i<NBINS;i+=NTHR) hist_g[i]=0u;
  if (tid==0){
    *gcount=0u;
    float mean=slg/2.0e5f;
    float var =sl2g/2.0e5f - mean*mean;
    float sg  =sqrtf(fmaxf(var,0.f));
    rparams[0]=gmax-24.f*sg;
    rparams[1]=(sg>0.f)?((float)NBINS/(32.f*sg)):0.f;
  }
}

// ---------- host ----------
extern "C" void kernel_launch(void* const* d_in, const int* in_sizes, int n_in,
                              void* d_out, int out_size, void* d_ws, size_t ws_size,
                              hipStream_t stream)
{
  const int*   x    = (const int*)d_in[0];
  const float* emb  = (const float*)d_in[1];
  const float* Wih  = (const float*)d_in[2];
  const float* Whh  = (const float*)d_in[3];
  const float* bih  = (const float*)d_in[4];
  const float* bhh  = (const float*)d_in[5];
  const float* Wout = (const float*)d_in[6];
  const float* bout = (const float*)d_in[7];
  float* out = (float*)d_out;

  char* ws = (char*)d_ws;
  float*    l_ws      = (float*)(ws + 0);         // 800000 B
  float*    partials  = (float*)(ws + 800000);    // 8192
  unsigned* mask_bits = (unsigned*)(ws + 808192); // 25000 (+pad)
  unsigned* inx_bits  = (unsigned*)(ws + 833280); // 25000 (+pad)
  unsigned* hist_g    = (unsigned*)(ws + 858368); // 4096
  unsigned* cand      = (unsigned*)(ws + 862464); // 16384
  unsigned* gcount    = (unsigned*)(ws + 878848); // 4 (pad 256)
  float*    rparams   = (float*)(ws + 879104);    // 8 (pad 256)
  float*    h_ws      = (float*)(ws + 879360);    // 512
  float*    c_ws      = (float*)(ws + 879872);    // 512 -> total 880384 B

  hipLaunchKernelGGL(k_init, dim3(1), dim3(1024), 0, stream,
                     x, bih, bhh, mask_bits, inx_bits, hist_g, gcount, rparams, h_ws, c_ws);

  for (int t=0; t<NSTEP; ++t){
    hipLaunchKernelGGL(k_logits, dim3(NBLK), dim3(NTHR), 0, stream,
                       Wout, bout, mask_bits, h_ws, rparams, l_ws, hist_g, partials);
    hipLaunchKernelGGL(k_emit, dim3(NBLK), dim3(NTHR), 0, stream,
                       l_ws, mask_bits, hist_g, partials, rparams, out, cand, gcount, t);
    hipLaunchKernelGGL(k_select, dim3(1), dim3(NTHR), 0, stream,
                       emb, Wih, Whh, bih, bhh, l_ws, partials, mask_bits, inx_bits,
                       hist_g, cand, gcount, rparams, h_ws, c_ws, out, t);
  }
}